// Round 2
// baseline (356.937 us; speedup 1.0000x reference)
//
#include <hip/hip_runtime.h>
#include <stdint.h>
#include <math.h>

// Disable implicit FP contraction globally: numpy never fuses a*a + s into
// fma. Explicit __builtin_fmaf below still emits v_fmac_f32 where we WANT fma
// (BLAS-style dot chain, single-rounded distance combine).
#pragma clang fp contract(off)

// Problem constants
#define B_   64
#define C_   64
#define HW_  1024
#define K_   512
#define N_   65536   // B_*HW_

// Output layout (float element offsets into d_out, reference return order)
#define OUT_Q    0ull                  // [B,C,H,W]  4194304
#define OUT_LOSS 4194304ull            // [B]        64
#define OUT_PERP 4194368ull            // scalar     1
#define OUT_ENC  4194369ull            // [N,K]      33554432
#define OUT_IDX  37748801ull           // [B,HW]     65536
#define OUT_DIST 37814337ull           // [N,K]      33554432

// Workspace layout (bytes)
#define WS_WT     0ull        // float[64*512]  transposed weight [c][k]
#define WS_WNORM  131072ull   // float[512]
#define WS_HIST   133120ull   // int[512]
#define WS_SUMSQ  135168ull   // float[64]
#define WS_ZERO_BYTES (512*4 + 64*4)

// ---------------------------------------------------------------------------
// Prep: wt[c*512+k] = w[k*64+c]; wnorm[k] = numpy-pairwise sum of w[k,:]^2
// numpy pairwise for n=64: r[j] = sum_i a[8i+j] (sequential), then
// ((r0+r1)+(r2+r3))+((r4+r5)+(r6+r7))
// ---------------------------------------------------------------------------
__global__ __launch_bounds__(256) void vq_prep(const float* __restrict__ w,
                                               float* __restrict__ wt,
                                               float* __restrict__ wnorm) {
  const int t = threadIdx.x;
  const int g = blockIdx.x * 256 + t;          // 0..32767
  const int c = g >> 9;
  const int k = g & 511;
  wt[g] = w[k * 64 + c];

  if (blockIdx.x < 16) {                       // 4096 threads = 512 rows x 8
    const int row = g >> 3;
    const int j = g & 7;
    float s = 0.f;
    for (int i = 0; i < 8; ++i) {
      float v = w[row * 64 + 8 * i + j];
      float sq = v * v;                        // rounded square (no fma fuse)
      s = s + sq;
    }
    float o1 = __shfl_xor(s, 1); s = s + o1;   // (r0+r1) etc.
    float o2 = __shfl_xor(s, 2); s = s + o2;   // ((r0+r1)+(r2+r3))
    float o4 = __shfl_xor(s, 4); s = s + o4;   // full numpy tree
    if (j == 0) wnorm[row] = s;
  }
}

// ---------------------------------------------------------------------------
// Main: one block = 32 rows (same batch b, consecutive hw).
// wave w owns rows 8w..8w+7; lane l owns k in {l + 64j}, j=0..7.
// ---------------------------------------------------------------------------
__global__ __launch_bounds__(256, 3) void vq_main(const float* __restrict__ x,
                                                  const float* __restrict__ wt,
                                                  const float* __restrict__ wnorm,
                                                  float* __restrict__ out,
                                                  int* __restrict__ hist,
                                                  float* __restrict__ sumsq) {
  __shared__ float x_s[64 * 32];    // [c][m]
  __shared__ float w_s[16 * 512];   // [cl][k], one 16-c chunk of wt
  __shared__ float wn_s[512];
  __shared__ float an_s[32];
  __shared__ int   kmin_s[32];
  __shared__ float red_s[4];

  const int t   = threadIdx.x;
  const int blk = blockIdx.x;       // 0..2047
  const int n0  = blk * 32;
  const int b   = n0 >> 10;
  const int hw0 = n0 & 1023;
  const int wid = t >> 6;           // wave 0..3
  const int l   = t & 63;

  // ---- stage x tile: x_s[c][m] = x[b, c, hw0+m], 2x float4 per thread ----
  {
    const float* xb = x + (size_t)b * 65536 + hw0;
    const int c0 = t >> 3;          // 0..31
    const int m4 = (t & 7) * 4;
    for (int i = 0; i < 2; ++i) {
      int c = i * 32 + c0;
      float4 v = *(const float4*)(xb + (size_t)c * 1024 + m4);
      *(float4*)(&x_s[c * 32 + m4]) = v;
    }
  }
  wn_s[t] = wnorm[t];
  wn_s[t + 256] = wnorm[t + 256];
  __syncthreads();

  // ---- a_n = ||x_row||^2 with exact numpy pairwise tree (8 lanes/row) ----
  {
    const int r = t >> 3, j = t & 7;
    float s = 0.f;
    for (int i = 0; i < 8; ++i) {
      float v = x_s[(8 * i + j) * 32 + r];
      float sq = v * v;
      s = s + sq;
    }
    float o1 = __shfl_xor(s, 1); s = s + o1;
    float o2 = __shfl_xor(s, 2); s = s + o2;
    float o4 = __shfl_xor(s, 4); s = s + o4;
    if (j == 0) an_s[r] = s;
  }

  float wn[8];
  for (int j = 0; j < 8; ++j) wn[j] = wn_s[l + 64 * j];

  // ---- dot products: acc[i][j] = x_row(8*wid+i) . w_col(l+64j) ----
  // Sequential fma chain over c=0..63 ascending (matches BLAS sgemm).
  float acc[8][8];
  for (int i = 0; i < 8; ++i)
    for (int j = 0; j < 8; ++j) acc[i][j] = 0.f;

#pragma unroll 1
  for (int cc = 0; cc < 4; ++cc) {
    __syncthreads();                 // protect w_s from previous chunk use
    for (int i = 0; i < 8; ++i) {    // stage 16 c-planes of wt: 32 KB
      int f4 = i * 256 + t;
      *(float4*)(&w_s[f4 * 4]) = *(const float4*)(wt + (size_t)cc * 8192 + f4 * 4);
    }
    __syncthreads();
#pragma unroll
    for (int cl = 0; cl < 16; ++cl) {
      const int c = cc * 16 + cl;
      float xv[8];
      *(float4*)(xv)     = *(const float4*)(&x_s[c * 32 + 8 * wid]);     // broadcast
      *(float4*)(xv + 4) = *(const float4*)(&x_s[c * 32 + 8 * wid + 4]); // broadcast
      float wv[8];
      for (int j = 0; j < 8; ++j) wv[j] = w_s[cl * 512 + l + 64 * j];    // 2-way, free
      for (int i = 0; i < 8; ++i)
        for (int j = 0; j < 8; ++j)
          acc[i][j] = __builtin_fmaf(xv[i], wv[j], acc[i][j]);
    }
  }

  // ---- distances, argmin, encodings, enc_idx, histogram ----
  float* const dist_o = out + OUT_DIST;
  float* const enc_o  = out + OUT_ENC;
  const int m_base = 8 * wid;
  for (int i = 0; i < 8; ++i) {
    const int m = m_base + i;
    const size_t n = (size_t)(n0 + m);
    const float an = an_s[m];
    float D[8];
    for (int j = 0; j < 8; ++j) {
      float tt = an + wn[j];                       // fl(a+b), numpy order
      D[j] = __builtin_fmaf(-2.f, acc[i][j], tt);  // fl(t - 2*dot), exact 2x
    }
    // lane-local argmin, first-occurrence semantics (k ascending with j)
    float vb = D[0]; int kb = l;
    for (int j = 1; j < 8; ++j) {
      if (D[j] < vb) { vb = D[j]; kb = l + 64 * j; }
    }
    // 64-lane butterfly; ties -> lowest k (numpy first-index)
    for (int d = 1; d < 64; d <<= 1) {
      float v2 = __shfl_xor(vb, d);
      int   k2 = __shfl_xor(kb, d);
      if (v2 < vb || (v2 == vb && k2 < kb)) { vb = v2; kb = k2; }
    }
    const size_t rb = n * 512 + l;
    for (int j = 0; j < 8; ++j) dist_o[rb + 64 * j] = D[j];           // coalesced
    for (int j = 0; j < 8; ++j) enc_o[rb + 64 * j] = (l + 64 * j == kb) ? 1.f : 0.f;
    if (l == i) {
      out[OUT_IDX + n] = (float)kb;
      atomicAdd(&hist[kb], 1);
      kmin_s[m] = kb;
    }
  }
  __syncthreads();   // kmin_s visible to all waves

  // ---- q_out (NCHW) + per-batch loss partial ----
  float lsum = 0.f;
  float* const q_o = out + OUT_Q;
  for (int it = 0; it < 8; ++it) {
    const int idx8 = it * 256 + t;
    const int c = idx8 >> 5, m = idx8 & 31;
    const int kb = kmin_s[m];
    const float qv = wt[(size_t)c * 512 + kb];   // L1/L2-cached gather
    const float xv = x_s[c * 32 + m];
    const float d = qv - xv;
    lsum = __builtin_fmaf(d, d, lsum);
    q_o[(size_t)b * 65536 + (size_t)c * 1024 + (hw0 + m)] = qv;  // coalesced
  }
  for (int d = 1; d < 64; d <<= 1) lsum += __shfl_xor(lsum, d);
  if (l == 0) red_s[wid] = lsum;
  __syncthreads();
  if (t == 0) {
    float s = (red_s[0] + red_s[1]) + (red_s[2] + red_s[3]);
    atomicAdd(sumsq + b, s);
  }
}

// ---------------------------------------------------------------------------
// Finalize: perplexity from histogram; loss[b] = 1.25 * sumsq[b]/65536
// ---------------------------------------------------------------------------
__global__ __launch_bounds__(512) void vq_fin(const int* __restrict__ hist,
                                              const float* __restrict__ sumsq,
                                              float* __restrict__ out) {
  __shared__ double red[8];
  const int t = threadIdx.x;
  double p = (double)hist[t] * (1.0 / 65536.0);
  double term = p * log(p + 1e-10);
  for (int d = 1; d < 64; d <<= 1) term += __shfl_xor(term, d);
  if ((t & 63) == 0) red[t >> 6] = term;
  __syncthreads();
  if (t == 0) {
    double s = 0.0;
    for (int i = 0; i < 8; ++i) s += red[i];
    out[OUT_PERP] = (float)exp(-s);
  }
  if (t < 64) {
    float m = sumsq[t] * (1.0f / 65536.0f);   // exact /2^16
    out[OUT_LOSS + t] = m + 0.25f * m;        // fl(m + fl(0.25m)), numpy order
  }
}

// ---------------------------------------------------------------------------
extern "C" void kernel_launch(void* const* d_in, const int* in_sizes, int n_in,
                              void* d_out, int out_size, void* d_ws, size_t ws_size,
                              hipStream_t stream) {
  const float* x = (const float*)d_in[0];   // [B,C,H,W] fp32
  const float* w = (const float*)d_in[1];   // [K,C] fp32
  float* out = (float*)d_out;
  char* ws = (char*)d_ws;
  float* wt    = (float*)(ws + WS_WT);
  float* wnorm = (float*)(ws + WS_WNORM);
  int*   hist  = (int*)  (ws + WS_HIST);
  float* sumsq = (float*)(ws + WS_SUMSQ);

  (void)hipMemsetAsync(ws + WS_HIST, 0, WS_ZERO_BYTES, stream);
  vq_prep<<<128, 256, 0, stream>>>(w, wt, wnorm);
  vq_main<<<2048, 256, 0, stream>>>(x, wt, wnorm, out, hist, sumsq);
  vq_fin<<<1, 512, 0, stream>>>(hist, sumsq, out);
}